// Round 8
// baseline (479.257 us; speedup 1.0000x reference)
//
#include <hip/hip_runtime.h>
#include <stdint.h>

#define TT 2048
#define DD 2048
#define NHH 16
#define HDD 128
#define BTT 4096   // B*T

typedef __attribute__((ext_vector_type(8))) short bf16x8;
typedef __attribute__((ext_vector_type(4))) float f32x4;

#define MF(a, b, c) __builtin_amdgcn_mfma_f32_16x16x32_bf16(a, b, c, 0, 0, 0)

__device__ __forceinline__ unsigned short f2bf(float f) {
    union { float f; uint32_t u; } v; v.f = f;
    uint32_t u = v.u;
    u += 0x7fffu + ((u >> 16) & 1u);   // RNE
    return (unsigned short)(u >> 16);
}

// async global->LDS, 16B per lane. LDS dest = wave-uniform base + lane*16B.
__device__ __forceinline__ void gld16(const unsigned short* g, unsigned short* l) {
    __builtin_amdgcn_global_load_lds(
        (const __attribute__((address_space(1))) unsigned int*)g,
        (__attribute__((address_space(3))) unsigned int*)l, 16, 0, 0);
}

// ---------------- weight fp32 -> bf16 cast ----------------
__global__ __launch_bounds__(256) void convert_w(const float* __restrict__ wq,
                                                 const float* __restrict__ wk,
                                                 const float* __restrict__ wv,
                                                 const float* __restrict__ wo,
                                                 unsigned short* __restrict__ out) {
    size_t gid = (size_t)blockIdx.x * 256 + threadIdx.x;
    size_t base = gid * 8;
    int which = (int)(base >> 22);
    const float* src = which == 0 ? wq : which == 1 ? wk : which == 2 ? wv : wo;
    size_t off = base & 4194303u;
    float4 a = ((const float4*)(src + off))[0];
    float4 b = ((const float4*)(src + off))[1];
    union { unsigned short us[8]; uint4 v; } pk;
    pk.us[0] = f2bf(a.x); pk.us[1] = f2bf(a.y); pk.us[2] = f2bf(a.z); pk.us[3] = f2bf(a.w);
    pk.us[4] = f2bf(b.x); pk.us[5] = f2bf(b.y); pk.us[6] = f2bf(b.z); pk.us[7] = f2bf(b.w);
    *(uint4*)(out + base) = pk.v;
}

// ---------------- RMSNorm fp32 -> bf16 ----------------
__global__ __launch_bounds__(256) void rmsnorm_k(const float* __restrict__ x,
                                                 const float* __restrict__ w,
                                                 unsigned short* __restrict__ xn) {
    const int row = blockIdx.x;
    const int tid = threadIdx.x;
    const float* xr = x + (size_t)row * DD;
    float4 a = ((const float4*)xr)[tid * 2];
    float4 b = ((const float4*)xr)[tid * 2 + 1];
    float ss = a.x*a.x + a.y*a.y + a.z*a.z + a.w*a.w
             + b.x*b.x + b.y*b.y + b.z*b.z + b.w*b.w;
    #pragma unroll
    for (int m = 1; m < 64; m <<= 1) ss += __shfl_xor(ss, m, 64);
    __shared__ float wss[4];
    if ((tid & 63) == 0) wss[tid >> 6] = ss;
    __syncthreads();
    float total = wss[0] + wss[1] + wss[2] + wss[3];
    float norm = sqrtf(total) * 0.022097086912079612f;
    float inv = 1.0f / (norm + 1e-8f);
    float4 wa = ((const float4*)w)[tid * 2];
    float4 wb = ((const float4*)w)[tid * 2 + 1];
    union { unsigned short us[8]; uint4 v; } pk;
    pk.us[0] = f2bf(wa.x * a.x * inv); pk.us[1] = f2bf(wa.y * a.y * inv);
    pk.us[2] = f2bf(wa.z * a.z * inv); pk.us[3] = f2bf(wa.w * a.w * inv);
    pk.us[4] = f2bf(wb.x * b.x * inv); pk.us[5] = f2bf(wb.y * b.y * inv);
    pk.us[6] = f2bf(wb.z * b.z * inv); pk.us[7] = f2bf(wb.w * b.w * inv);
    ((uint4*)(xn + (size_t)row * DD))[tid] = pk.v;
}

// ---------------- 128x256 reg-staged L2-cached GEMM core (R8) ----------------
// Fetch-roofline diagnosis: all GEMM variants pinned at ~540 TF = tile-fetch 1.15GB /
// 6.1 TB/s L2-miss BW. gld16 staging appears to defeat cross-block L2 sharing. R8:
// normal vector loads (L2-cacheable) -> VGPR -> ds_write. BK=32, dbuf 48KB total ->
// 2 blocks/CU (16 waves/CU, 2x R7's TLP). Chunk-major stripe LDS layout: stage lane l
// holds (row=l&15, kchunk=l>>4) -> dest lane*16B linear; frag read (stripe, lq, l15)
// contiguous 256B/16-lane -> conflict-free both sides, no XOR needed.
// One barrier/tile; loads for kt+1 issued at kt start (T14 early-issue).
__device__ __forceinline__ void gemm128x256_core(const unsigned short* __restrict__ Ag,
                                                 const unsigned short* __restrict__ Bg,
                                                 unsigned short* lds, f32x4 acc[4][4]) {
    const int tid = threadIdx.x;
    const int wave = tid >> 6, lane = tid & 63;
    const int wm = wave >> 2, wn = wave & 3;
    const int l15 = lane & 15, lq = lane >> 4;
    // staging global addresses (wave w: A-stripe w, B-stripes 2w,2w+1)
    const unsigned short* ga  = Ag + (size_t)(wave * 16 + l15) * DD + lq * 8;
    const unsigned short* gb0 = Bg + (size_t)(wave * 32 + l15) * DD + lq * 8;
    const unsigned short* gb1 = Bg + (size_t)(wave * 32 + 16 + l15) * DD + lq * 8;
    // staging LDS dests (elements)
    const int da  = wave * 512 + lane * 8;
    const int db0 = 4096 + wave * 1024 + lane * 8;
    const int db1 = 4096 + wave * 1024 + 512 + lane * 8;
    // frag read bases: stripe s at s*512, within: lq*128 + l15*8
    const int ra = (wm * 4) * 512 + lq * 128 + l15 * 8;
    const int rb = 4096 + (wn * 4) * 512 + lq * 128 + l15 * 8;

    // ---- prologue: stage tile 0 ----
    uint4 sA  = *(const uint4*)(ga);
    uint4 sB0 = *(const uint4*)(gb0);
    uint4 sB1 = *(const uint4*)(gb1);
    *(uint4*)(lds + da)  = sA;
    *(uint4*)(lds + db0) = sB0;
    *(uint4*)(lds + db1) = sB1;
    asm volatile("s_waitcnt lgkmcnt(0)" ::: "memory");
    __builtin_amdgcn_s_barrier();

    for (int kt = 0; kt < 64; kt++) {
        const int cur = (kt & 1) ? 12288 : 0;
        const int nxt = 12288 - cur;
        // ---- early-issue loads for tile kt+1 (hide under frag reads + MFMA) ----
        if (kt + 1 < 64) {
            const int ko = (kt + 1) * 32;
            sA  = *(const uint4*)(ga + ko);
            sB0 = *(const uint4*)(gb0 + ko);
            sB1 = *(const uint4*)(gb1 + ko);
            __builtin_amdgcn_sched_barrier(0);
        }
        const unsigned short* ac = lds + cur + ra;
        const unsigned short* bc = lds + cur + rb;
        bf16x8 a[4], b[4];
        #pragma unroll
        for (int i = 0; i < 4; i++) a[i] = *(const bf16x8*)(ac + i * 512);
        #pragma unroll
        for (int n = 0; n < 4; n++) b[n] = *(const bf16x8*)(bc + n * 512);
        asm volatile("s_waitcnt lgkmcnt(0)" ::: "memory");
        __builtin_amdgcn_sched_barrier(0);
        __builtin_amdgcn_s_setprio(1);
        #pragma unroll
        for (int i = 0; i < 4; i++)
            #pragma unroll
            for (int n = 0; n < 4; n++)
                acc[i][n] = MF(a[i], b[n], acc[i][n]);
        __builtin_amdgcn_s_setprio(0);
        // ---- commit kt+1 into the other buffer (compiler inserts vmcnt before use) ----
        if (kt + 1 < 64) {
            *(uint4*)(lds + nxt + da)  = sA;
            *(uint4*)(lds + nxt + db0) = sB0;
            *(uint4*)(lds + nxt + db1) = sB1;
            asm volatile("s_waitcnt lgkmcnt(0)" ::: "memory");
            __builtin_amdgcn_sched_barrier(0);
        }
        __builtin_amdgcn_s_barrier();
    }
}

// fused QKV: 768 blocks (32x8x3) x 512 thr; XCD swizzle -> same-B-panel blocks per XCD
__global__ __launch_bounds__(512, 4) void gemm_qkv(const unsigned short* __restrict__ A,
                                                   const unsigned short* __restrict__ W3,
                                                   unsigned short* __restrict__ O3) {
    __shared__ __align__(16) unsigned short lds[24576];   // 48 KiB, 2 bufs
    const int orig = blockIdx.y * 32 + blockIdx.x;        // grid (32, 24)
    const int id = (orig & 7) * 96 + (orig >> 3);         // bijective XCD swizzle (768%8==0)
    const int which = id >> 8;
    const int rem = id & 255;
    const int bn = rem >> 5, bm = rem & 31;               // consecutive ids share B panel
    const unsigned short* Bw = W3 + (size_t)which * DD * DD;
    unsigned short* C = O3 + (size_t)which * BTT * DD;
    const int m0 = bm * 128, n0 = bn * 256;
    const f32x4 zf = {0.f, 0.f, 0.f, 0.f};
    f32x4 acc[4][4];
    #pragma unroll
    for (int m = 0; m < 4; m++)
        #pragma unroll
        for (int n = 0; n < 4; n++) acc[m][n] = zf;
    gemm128x256_core(A + (size_t)m0 * DD, Bw + (size_t)n0 * DD, lds, acc);
    const int wave = threadIdx.x >> 6, lane = threadIdx.x & 63;
    const int wm = wave >> 2, wn = wave & 3;
    const int l15 = lane & 15, lq = lane >> 4;
    #pragma unroll
    for (int m = 0; m < 4; m++) {
        const int row = m0 + wm * 64 + m * 16 + lq * 4;
        #pragma unroll
        for (int n = 0; n < 4; n++) {
            const int col = n0 + wn * 64 + n * 16 + l15;
            #pragma unroll
            for (int r = 0; r < 4; r++)
                C[(size_t)(row + r) * DD + col] = f2bf(acc[m][n][r]);
        }
    }
}

// final proj, fp32 out: 256 blocks (32x8) x 512 thr; same-bn per XCD
__global__ __launch_bounds__(512, 4) void gemm_out(const unsigned short* __restrict__ A,
                                                   const unsigned short* __restrict__ Bw,
                                                   float* __restrict__ C) {
    __shared__ __align__(16) unsigned short lds[24576];   // 48 KiB, 2 bufs
    const int orig = blockIdx.y * 32 + blockIdx.x;        // grid (32, 8)
    const int id = (orig & 7) * 32 + (orig >> 3);         // bijective XCD swizzle (256%8==0)
    const int bn = id >> 5, bm = id & 31;
    const int m0 = bm * 128, n0 = bn * 256;
    const f32x4 zf = {0.f, 0.f, 0.f, 0.f};
    f32x4 acc[4][4];
    #pragma unroll
    for (int m = 0; m < 4; m++)
        #pragma unroll
        for (int n = 0; n < 4; n++) acc[m][n] = zf;
    gemm128x256_core(A + (size_t)m0 * DD, Bw + (size_t)n0 * DD, lds, acc);
    const int wave = threadIdx.x >> 6, lane = threadIdx.x & 63;
    const int wm = wave >> 2, wn = wave & 3;
    const int l15 = lane & 15, lq = lane >> 4;
    #pragma unroll
    for (int m = 0; m < 4; m++) {
        const int row = m0 + wm * 64 + m * 16 + lq * 4;
        #pragma unroll
        for (int n = 0; n < 4; n++) {
            const int col = n0 + wn * 64 + n * 16 + l15;
            #pragma unroll
            for (int r = 0; r < 4; r++)
                C[(size_t)(row + r) * DD + col] = acc[m][n][r];
        }
    }
}

// ---------------- fused causal flash attention (R6 body + R8 XCD head-grouping) ----------------
// R8: remap block -> (pair, h, b) so all 16 pair-blocks of one (h,b) land on ONE XCD
// (assuming round-robin linear-id -> XCD dispatch). 4 heads/XCD = 4MB K/V working set
// = L2-sized -> K/V reads become L2 hits. Predicted FETCH 255MB -> ~80MB.
__global__ __launch_bounds__(256) void attn_fused(const unsigned short* __restrict__ q,
                                                  const unsigned short* __restrict__ k,
                                                  const unsigned short* __restrict__ v,
                                                  unsigned short* __restrict__ o) {
    constexpr int LPP = 72;   // 64 + 8 pad
    __shared__ __align__(16) unsigned short Ks[2][64 * 128];
    __shared__ __align__(16) unsigned short Vts[128 * 64];
    __shared__ __align__(16) unsigned short Ps[4 * 16 * LPP];
    // XCD head-grouping remap: lin = pair + 16*h + 256*b; XCD = lin&7 (round-robin).
    // group g = (lin&7)*4 + ((lin>>3)>>4) in 0..31 -> (h,b); pair = (lin>>3)&15.
    const int lin = blockIdx.x + (blockIdx.y << 4) + (blockIdx.z << 8);
    const int slot = lin >> 3;
    const int g = ((lin & 7) << 2) + (slot >> 4);
    const int pairi = slot & 15;
    const int h = g & 15, b = g >> 4;
    const int tid = threadIdx.x, wave = tid >> 6, lane = tid & 63;
    const int l15 = lane & 15, lq = lane >> 4;
    const size_t rowbase = (size_t)b * TT;
    const int hcol = h * HDD;
    const float scale = 0.08838834764831845f;  // HD^-0.5
    unsigned short* Pw = Ps + wave * 16 * LPP;
    const f32x4 zf = {0.f, 0.f, 0.f, 0.f};

    uint4 vr0, vr1, vr2, vr3;
    const int pr = tid >> 3;            // 0..31
    const int hc = (tid & 7) * 16;      // 0,16,...,112
    const int vsw0 = (2 * pr) ^ (((hc >> 3) & 7) << 3);
    const int vsw1 = (2 * pr) ^ ((((hc + 8) >> 3) & 7) << 3);

    const int klrow = lane >> 4;        // 0..3
    const int klch  = lane & 15;

    for (int half = 0; half < 2; half++) {
        const int qj = (half == 0) ? pairi : 31 - pairi;
        const int qt0 = qj * 64;
        bf16x8 aq[4];
        {
            const unsigned short* qrp = q + (rowbase + qt0 + wave * 16 + l15) * DD + hcol;
            #pragma unroll
            for (int kk = 0; kk < 4; kk++)
                aq[kk] = *(const bf16x8*)(qrp + kk * 32 + lq * 8);
        }
        f32x4 acc_o[8];
        #pragma unroll
        for (int jh = 0; jh < 8; jh++) acc_o[jh] = zf;
        float m_i[4], l_i[4];
        #pragma unroll
        for (int r = 0; r < 4; r++) { m_i[r] = -1e30f; l_i[r] = 0.f; }
        const int qp0 = qt0 + wave * 16 + lq * 4;
        const int nkt = qj + 1;

        __syncthreads();
        {
            const unsigned short* kg = k + rowbase * DD + hcol;
            const unsigned short* vg = v + rowbase * DD + hcol;
            #pragma unroll
            for (int i = 0; i < 4; i++) {
                const int r0 = wave * 16 + i * 4;
                const int row = r0 + klrow;
                const int gch = klch ^ (row & 7);
                gld16(kg + (size_t)row * DD + gch * 8, &Ks[0][r0 * 128]);
            }
            vr0 = *(const uint4*)(vg + (size_t)(2 * pr) * DD + hc);
            vr1 = *(const uint4*)(vg + (size_t)(2 * pr) * DD + hc + 8);
            vr2 = *(const uint4*)(vg + (size_t)(2 * pr + 1) * DD + hc);
            vr3 = *(const uint4*)(vg + (size_t)(2 * pr + 1) * DD + hc + 8);
        }

        for (int kt = 0; kt < nkt; kt++) {
            const int cur = kt & 1;
            __syncthreads();   // barrier A: drains K/V prefetch; prior tile reads done
            if (kt + 1 < nkt) {
                const unsigned short* kg = k + (rowbase + (kt + 1) * 64) * DD + hcol;
                #pragma unroll
                for (int i = 0; i < 4; i++) {
                    const int r0 = wave * 16 + i * 4;
                    const int row = r0 + klrow;
                    const int gch = klch ^ (row & 7);
                    gld16(kg + (size_t)row * DD + gch * 8, &Ks[cur ^ 1][r0 * 128]);
                }
            }
            {
                const unsigned short* s0 = (const unsigned short*)&vr0;
                const unsigned short* s1 = (const unsigned short*)&vr1;
                const unsigned short* s2 = (const unsigned short*)&vr2;
                const unsigned short* s3 = (const unsigned short*)&vr3;
                #pragma unroll
                for (int jj = 0; jj < 8; jj++) {
                    *(uint32_t*)(&Vts[(hc + jj) * 64 + vsw0]) =
                        (uint32_t)s0[jj] | ((uint32_t)s2[jj] << 16);
                    *(uint32_t*)(&Vts[(hc + 8 + jj) * 64 + vsw1]) =
                        (uint32_t)s1[jj] | ((uint32_t)s3[jj] << 16);
                }
            }
            if (kt + 1 < nkt) {
                const unsigned short* vg = v + (rowbase + (kt + 1) * 64) * DD + hcol;
                vr0 = *(const uint4*)(vg + (size_t)(2 * pr) * DD + hc);
                vr1 = *(const uint4*)(vg + (size_t)(2 * pr) * DD + hc + 8);
                vr2 = *(const uint4*)(vg + (size_t)(2 * pr + 1) * DD + hc);
                vr3 = *(const uint4*)(vg + (size_t)(2 * pr + 1) * DD + hc + 8);
            }
            const unsigned short* ksc = &Ks[cur][0];
            f32x4 accs[4];
            #pragma unroll
            for (int j = 0; j < 4; j++) accs[j] = zf;
            __builtin_amdgcn_s_setprio(1);
            #pragma unroll
            for (int j = 0; j < 4; j++)
                #pragma unroll
                for (int kk = 0; kk < 4; kk++) {
                    bf16x8 bk = *(const bf16x8*)(&ksc[(j * 16 + l15) * 128 +
                                                      (((kk * 4 + lq) ^ (l15 & 7)) * 8)]);
                    accs[j] = MF(aq[kk], bk, accs[j]);
                }
            __builtin_amdgcn_s_setprio(0);
            const int kbase = kt * 64;
            float rowmax[4] = {-1e30f, -1e30f, -1e30f, -1e30f};
            #pragma unroll
            for (int j = 0; j < 4; j++) {
                const int kp = kbase + j * 16 + l15;
                #pragma unroll
                for (int r = 0; r < 4; r++) {
                    float s = accs[j][r] * scale;
                    s = (kp > qp0 + r) ? -1e30f : s;
                    accs[j][r] = s;
                    rowmax[r] = fmaxf(rowmax[r], s);
                }
            }
            #pragma unroll
            for (int r = 0; r < 4; r++) {
                float mx = rowmax[r];
                mx = fmaxf(mx, __shfl_xor(mx, 1, 64));
                mx = fmaxf(mx, __shfl_xor(mx, 2, 64));
                mx = fmaxf(mx, __shfl_xor(mx, 4, 64));
                mx = fmaxf(mx, __shfl_xor(mx, 8, 64));
                float m_new = fmaxf(m_i[r], mx);
                float al = __expf(m_i[r] - m_new);
                m_i[r] = m_new;
                l_i[r] *= al;
                #pragma unroll
                for (int jh = 0; jh < 8; jh++) acc_o[jh][r] *= al;
            }
            float rowsum[4] = {0.f, 0.f, 0.f, 0.f};
            #pragma unroll
            for (int j = 0; j < 4; j++)
                #pragma unroll
                for (int r = 0; r < 4; r++) {
                    float p = __expf(accs[j][r] - m_i[r]);
                    rowsum[r] += p;
                    Pw[(lq * 4 + r) * LPP + j * 16 + l15] = f2bf(p);
                }
            #pragma unroll
            for (int r = 0; r < 4; r++) {
                float s = rowsum[r];
                s += __shfl_xor(s, 1, 64);
                s += __shfl_xor(s, 2, 64);
                s += __shfl_xor(s, 4, 64);
                s += __shfl_xor(s, 8, 64);
                l_i[r] += s;
            }
            __syncthreads();   // barrier B: V(kt) scatter + P visible
            bf16x8 ap[2];
            #pragma unroll
            for (int kk = 0; kk < 2; kk++)
                ap[kk] = *(const bf16x8*)(&Pw[l15 * LPP + kk * 32 + lq * 8]);
            __builtin_amdgcn_s_setprio(1);
            #pragma unroll
            for (int jh = 0; jh < 8; jh++) {
                const int hd = jh * 16 + l15;
                const int vswz = ((hd >> 3) & 7) << 3;
                #pragma unroll
                for (int kk = 0; kk < 2; kk++) {
                    bf16x8 bv = *(const bf16x8*)(&Vts[hd * 64 + ((kk * 32 + lq * 8) ^ vswz)]);
                    acc_o[jh] = MF(ap[kk], bv, acc_o[jh]);
                }
            }
            __builtin_amdgcn_s_setprio(0);
        }
        #pragma unroll
        for (int jh = 0; jh < 8; jh++) {
            const int col = hcol + jh * 16 + l15;
            #pragma unroll
            for (int r = 0; r < 4; r++)
                o[(rowbase + qp0 + r) * DD + col] = f2bf(acc_o[jh][r] * (1.0f / l_i[r]));
        }
    }
}

extern "C" void kernel_launch(void* const* d_in, const int* in_sizes, int n_in,
                              void* d_out, int out_size, void* d_ws, size_t ws_size,
                              hipStream_t stream) {
    const float* x      = (const float*)d_in[0];
    // d_in[1] = attn_mask: deterministic causal tril -> handled analytically
    const float* w_norm = (const float*)d_in[2];
    const float* wq     = (const float*)d_in[3];
    const float* wk     = (const float*)d_in[4];
    const float* wv     = (const float*)d_in[5];
    const float* wo     = (const float*)d_in[6];

    unsigned short* wbf = (unsigned short*)d_ws;                 // [4][D*D]
    unsigned short* xn  = wbf + (size_t)4 * DD * DD;             // [BT][D]
    unsigned short* qb  = xn + (size_t)BTT * DD;
    unsigned short* kb  = qb + (size_t)BTT * DD;
    unsigned short* vb  = kb + (size_t)BTT * DD;
    unsigned short* ab  = vb + (size_t)BTT * DD;

    convert_w<<<8192, 256, 0, stream>>>(wq, wk, wv, wo, wbf);
    rmsnorm_k<<<BTT, 256, 0, stream>>>(x, w_norm, xn);
    dim3 gqkv(32, 24);
    gemm_qkv<<<gqkv, 512, 0, stream>>>(xn, wbf, qb);
    dim3 gattn(16, NHH, 2);
    attn_fused<<<gattn, 256, 0, stream>>>(qb, kb, vb, ab);
    dim3 gout(32, 8);
    gemm_out<<<gout, 512, 0, stream>>>(ab, wbf + (size_t)3 * DD * DD, (float*)d_out);
}

// Round 9
// 455.865 us; speedup vs baseline: 1.0513x; 1.0513x over previous
//
#include <hip/hip_runtime.h>
#include <stdint.h>

#define TT 2048
#define DD 2048
#define NHH 16
#define HDD 128
#define BTT 4096   // B*T

typedef __attribute__((ext_vector_type(8))) short bf16x8;
typedef __attribute__((ext_vector_type(4))) float f32x4;

#define MF(a, b, c) __builtin_amdgcn_mfma_f32_16x16x32_bf16(a, b, c, 0, 0, 0)

__device__ __forceinline__ unsigned short f2bf(float f) {
    union { float f; uint32_t u; } v; v.f = f;
    uint32_t u = v.u;
    u += 0x7fffu + ((u >> 16) & 1u);   // RNE
    return (unsigned short)(u >> 16);
}

// async global->LDS, 16B per lane. LDS dest = wave-uniform base + lane*16B.
__device__ __forceinline__ void gld16(const unsigned short* g, unsigned short* l) {
    __builtin_amdgcn_global_load_lds(
        (const __attribute__((address_space(1))) unsigned int*)g,
        (__attribute__((address_space(3))) unsigned int*)l, 16, 0, 0);
}

// ---------------- weight fp32 -> bf16 cast ----------------
__global__ __launch_bounds__(256) void convert_w(const float* __restrict__ wq,
                                                 const float* __restrict__ wk,
                                                 const float* __restrict__ wv,
                                                 const float* __restrict__ wo,
                                                 unsigned short* __restrict__ out) {
    size_t gid = (size_t)blockIdx.x * 256 + threadIdx.x;
    size_t base = gid * 8;
    int which = (int)(base >> 22);
    const float* src = which == 0 ? wq : which == 1 ? wk : which == 2 ? wv : wo;
    size_t off = base & 4194303u;
    float4 a = ((const float4*)(src + off))[0];
    float4 b = ((const float4*)(src + off))[1];
    union { unsigned short us[8]; uint4 v; } pk;
    pk.us[0] = f2bf(a.x); pk.us[1] = f2bf(a.y); pk.us[2] = f2bf(a.z); pk.us[3] = f2bf(a.w);
    pk.us[4] = f2bf(b.x); pk.us[5] = f2bf(b.y); pk.us[6] = f2bf(b.z); pk.us[7] = f2bf(b.w);
    *(uint4*)(out + base) = pk.v;
}

// ---------------- RMSNorm fp32 -> bf16 ----------------
__global__ __launch_bounds__(256) void rmsnorm_k(const float* __restrict__ x,
                                                 const float* __restrict__ w,
                                                 unsigned short* __restrict__ xn) {
    const int row = blockIdx.x;
    const int tid = threadIdx.x;
    const float* xr = x + (size_t)row * DD;
    float4 a = ((const float4*)xr)[tid * 2];
    float4 b = ((const float4*)xr)[tid * 2 + 1];
    float ss = a.x*a.x + a.y*a.y + a.z*a.z + a.w*a.w
             + b.x*b.x + b.y*b.y + b.z*b.z + b.w*b.w;
    #pragma unroll
    for (int m = 1; m < 64; m <<= 1) ss += __shfl_xor(ss, m, 64);
    __shared__ float wss[4];
    if ((tid & 63) == 0) wss[tid >> 6] = ss;
    __syncthreads();
    float total = wss[0] + wss[1] + wss[2] + wss[3];
    float norm = sqrtf(total) * 0.022097086912079612f;
    float inv = 1.0f / (norm + 1e-8f);
    float4 wa = ((const float4*)w)[tid * 2];
    float4 wb = ((const float4*)w)[tid * 2 + 1];
    union { unsigned short us[8]; uint4 v; } pk;
    pk.us[0] = f2bf(wa.x * a.x * inv); pk.us[1] = f2bf(wa.y * a.y * inv);
    pk.us[2] = f2bf(wa.z * a.z * inv); pk.us[3] = f2bf(wa.w * a.w * inv);
    pk.us[4] = f2bf(wb.x * b.x * inv); pk.us[5] = f2bf(wb.y * b.y * inv);
    pk.us[6] = f2bf(wb.z * b.z * inv); pk.us[7] = f2bf(wb.w * b.w * inv);
    ((uint4*)(xn + (size_t)row * DD))[tid] = pk.v;
}

// ---------------- 128x256 reg-staged depth-2 counted-vmcnt GEMM core (R9) ----------------
// R8 proved: normal loads engage cross-block L2 sharing (FETCH 1.15GB->144MB, conflicts=0)
// but depth-1 pipeline stalls ~900cy/tile on the commit's implicit vmcnt(0).
// R9: prefetch depth 2 with two named reg sets. Iteration kt: issue tile kt+2; compute kt;
// commit kt+1 (issued a FULL iteration ago) with vmcnt(3) -- only the oldest 3 loads are
// waited, kt+2's 3 stay in flight. Cover per load ~2 tile-times >= HBM 900cy.
// Alternating even/odd bodies keep all regs statically named (rule #20).
__device__ __forceinline__ void gemm128x256_core(const unsigned short* __restrict__ Ag,
                                                 const unsigned short* __restrict__ Bg,
                                                 unsigned short* lds, f32x4 acc[4][4]) {
    const int tid = threadIdx.x;
    const int wave = tid >> 6, lane = tid & 63;
    const int wm = wave >> 2, wn = wave & 3;
    const int l15 = lane & 15, lq = lane >> 4;
    // staging global addresses (wave w: A-stripe w, B-stripes 2w,2w+1)
    const unsigned short* ga  = Ag + (size_t)(wave * 16 + l15) * DD + lq * 8;
    const unsigned short* gb0 = Bg + (size_t)(wave * 32 + l15) * DD + lq * 8;
    const unsigned short* gb1 = Bg + (size_t)(wave * 32 + 16 + l15) * DD + lq * 8;
    // staging LDS dests (elements), chunk-major stripes (conflict-free, R8-verified)
    const int da  = wave * 512 + lane * 8;
    const int db0 = 4096 + wave * 1024 + lane * 8;
    const int db1 = 4096 + wave * 1024 + 512 + lane * 8;
    const int ra = (wm * 4) * 512 + lq * 128 + l15 * 8;
    const int rb = 4096 + (wn * 4) * 512 + lq * 128 + l15 * 8;

    uint4 pA, pB0, pB1, qA, qB0, qB1;

    // ---- prologue: tile0 -> commit buf0; tile1 -> p regs (stays in flight) ----
    pA  = *(const uint4*)(ga);
    pB0 = *(const uint4*)(gb0);
    pB1 = *(const uint4*)(gb1);
    asm volatile("s_waitcnt vmcnt(0)" ::: "memory");
    *(uint4*)(lds + da)  = pA;
    *(uint4*)(lds + db0) = pB0;
    *(uint4*)(lds + db1) = pB1;
    pA  = *(const uint4*)(ga + 32);
    pB0 = *(const uint4*)(gb0 + 32);
    pB1 = *(const uint4*)(gb1 + 32);
    asm volatile("s_waitcnt lgkmcnt(0)" ::: "memory");
    __builtin_amdgcn_s_barrier();

    auto body = [&](int kt, int cur, int nxt,
                    uint4& cpA, uint4& cpB0, uint4& cpB1,
                    uint4& cqA, uint4& cqB0, uint4& cqB1) {
        const bool h2 = (kt + 2 < 64);
        if (h2) {
            const int ko = (kt + 2) * 32;
            cqA  = *(const uint4*)(ga + ko);
            cqB0 = *(const uint4*)(gb0 + ko);
            cqB1 = *(const uint4*)(gb1 + ko);
        }
        const unsigned short* ac = lds + cur + ra;
        const unsigned short* bc = lds + cur + rb;
        bf16x8 a[4], b[4];
        #pragma unroll
        for (int i = 0; i < 4; i++) a[i] = *(const bf16x8*)(ac + i * 512);
        #pragma unroll
        for (int n = 0; n < 4; n++) b[n] = *(const bf16x8*)(bc + n * 512);
        asm volatile("s_waitcnt lgkmcnt(0)" ::: "memory");
        __builtin_amdgcn_sched_barrier(0);
        __builtin_amdgcn_s_setprio(1);
        #pragma unroll
        for (int i = 0; i < 4; i++)
            #pragma unroll
            for (int n = 0; n < 4; n++)
                acc[i][n] = MF(a[i], b[n], acc[i][n]);
        __builtin_amdgcn_s_setprio(0);
        if (kt + 1 < 64) {
            // counted wait: oldest 3 (tile kt+1, issued last iteration) complete;
            // tile kt+2's 3 loads stay in flight across the barrier.
            if (h2) { asm volatile("s_waitcnt vmcnt(3)" ::: "memory"); }
            else    { asm volatile("s_waitcnt vmcnt(0)" ::: "memory"); }
            __builtin_amdgcn_sched_barrier(0);
            *(uint4*)(lds + nxt + da)  = cpA;
            *(uint4*)(lds + nxt + db0) = cpB0;
            *(uint4*)(lds + nxt + db1) = cpB1;
            asm volatile("s_waitcnt lgkmcnt(0)" ::: "memory");
            __builtin_amdgcn_sched_barrier(0);
        }
        __builtin_amdgcn_s_barrier();
    };

    for (int k2 = 0; k2 < 32; k2++) {
        body(2 * k2,     0,     12288, pA, pB0, pB1, qA, qB0, qB1);
        body(2 * k2 + 1, 12288, 0,     qA, qB0, qB1, pA, pB0, pB1);
    }
}

// fused QKV: 768 blocks (32x8x3) x 512 thr; XCD swizzle -> same-B-panel blocks per XCD
__global__ __launch_bounds__(512) void gemm_qkv(const unsigned short* __restrict__ A,
                                                const unsigned short* __restrict__ W3,
                                                unsigned short* __restrict__ O3) {
    __shared__ __align__(16) unsigned short lds[24576];   // 48 KiB, 2 bufs
    const int orig = blockIdx.y * 32 + blockIdx.x;        // grid (32, 24)
    const int id = (orig & 7) * 96 + (orig >> 3);         // bijective XCD swizzle (768%8==0)
    const int which = id >> 8;
    const int rem = id & 255;
    const int bn = rem >> 5, bm = rem & 31;               // consecutive ids share B panel
    const unsigned short* Bw = W3 + (size_t)which * DD * DD;
    unsigned short* C = O3 + (size_t)which * BTT * DD;
    const int m0 = bm * 128, n0 = bn * 256;
    const f32x4 zf = {0.f, 0.f, 0.f, 0.f};
    f32x4 acc[4][4];
    #pragma unroll
    for (int m = 0; m < 4; m++)
        #pragma unroll
        for (int n = 0; n < 4; n++) acc[m][n] = zf;
    gemm128x256_core(A + (size_t)m0 * DD, Bw + (size_t)n0 * DD, lds, acc);
    const int wave = threadIdx.x >> 6, lane = threadIdx.x & 63;
    const int wm = wave >> 2, wn = wave & 3;
    const int l15 = lane & 15, lq = lane >> 4;
    #pragma unroll
    for (int m = 0; m < 4; m++) {
        const int row = m0 + wm * 64 + m * 16 + lq * 4;
        #pragma unroll
        for (int n = 0; n < 4; n++) {
            const int col = n0 + wn * 64 + n * 16 + l15;
            #pragma unroll
            for (int r = 0; r < 4; r++)
                C[(size_t)(row + r) * DD + col] = f2bf(acc[m][n][r]);
        }
    }
}

// final proj, fp32 out: 256 blocks (32x8) x 512 thr
__global__ __launch_bounds__(512) void gemm_out(const unsigned short* __restrict__ A,
                                                const unsigned short* __restrict__ Bw,
                                                float* __restrict__ C) {
    __shared__ __align__(16) unsigned short lds[24576];   // 48 KiB, 2 bufs
    const int orig = blockIdx.y * 32 + blockIdx.x;        // grid (32, 8)
    const int id = (orig & 7) * 32 + (orig >> 3);         // bijective XCD swizzle (256%8==0)
    const int bn = id >> 5, bm = id & 31;
    const int m0 = bm * 128, n0 = bn * 256;
    const f32x4 zf = {0.f, 0.f, 0.f, 0.f};
    f32x4 acc[4][4];
    #pragma unroll
    for (int m = 0; m < 4; m++)
        #pragma unroll
        for (int n = 0; n < 4; n++) acc[m][n] = zf;
    gemm128x256_core(A + (size_t)m0 * DD, Bw + (size_t)n0 * DD, lds, acc);
    const int wave = threadIdx.x >> 6, lane = threadIdx.x & 63;
    const int wm = wave >> 2, wn = wave & 3;
    const int l15 = lane & 15, lq = lane >> 4;
    #pragma unroll
    for (int m = 0; m < 4; m++) {
        const int row = m0 + wm * 64 + m * 16 + lq * 4;
        #pragma unroll
        for (int n = 0; n < 4; n++) {
            const int col = n0 + wn * 64 + n * 16 + l15;
            #pragma unroll
            for (int r = 0; r < 4; r++)
                C[(size_t)(row + r) * DD + col] = acc[m][n][r];
        }
    }
}

// ---------------- fused causal flash attention, paired q-tiles (R7 mapping restored) ----------------
__global__ __launch_bounds__(256) void attn_fused(const unsigned short* __restrict__ q,
                                                  const unsigned short* __restrict__ k,
                                                  const unsigned short* __restrict__ v,
                                                  unsigned short* __restrict__ o) {
    constexpr int LPP = 72;   // 64 + 8 pad
    __shared__ __align__(16) unsigned short Ks[2][64 * 128];
    __shared__ __align__(16) unsigned short Vts[128 * 64];
    __shared__ __align__(16) unsigned short Ps[4 * 16 * LPP];
    const int h = blockIdx.y, b = blockIdx.z;
    const int tid = threadIdx.x, wave = tid >> 6, lane = tid & 63;
    const int l15 = lane & 15, lq = lane >> 4;
    const size_t rowbase = (size_t)b * TT;
    const int hcol = h * HDD;
    const float scale = 0.08838834764831845f;  // HD^-0.5
    unsigned short* Pw = Ps + wave * 16 * LPP;
    const f32x4 zf = {0.f, 0.f, 0.f, 0.f};

    uint4 vr0, vr1, vr2, vr3;
    const int pr = tid >> 3;            // 0..31
    const int hc = (tid & 7) * 16;      // 0,16,...,112
    const int vsw0 = (2 * pr) ^ (((hc >> 3) & 7) << 3);
    const int vsw1 = (2 * pr) ^ ((((hc + 8) >> 3) & 7) << 3);

    const int klrow = lane >> 4;        // 0..3
    const int klch  = lane & 15;

    for (int half = 0; half < 2; half++) {
        const int qj = (half == 0) ? blockIdx.x : 31 - blockIdx.x;
        const int qt0 = qj * 64;
        bf16x8 aq[4];
        {
            const unsigned short* qrp = q + (rowbase + qt0 + wave * 16 + l15) * DD + hcol;
            #pragma unroll
            for (int kk = 0; kk < 4; kk++)
                aq[kk] = *(const bf16x8*)(qrp + kk * 32 + lq * 8);
        }
        f32x4 acc_o[8];
        #pragma unroll
        for (int jh = 0; jh < 8; jh++) acc_o[jh] = zf;
        float m_i[4], l_i[4];
        #pragma unroll
        for (int r = 0; r < 4; r++) { m_i[r] = -1e30f; l_i[r] = 0.f; }
        const int qp0 = qt0 + wave * 16 + lq * 4;
        const int nkt = qj + 1;

        __syncthreads();
        {
            const unsigned short* kg = k + rowbase * DD + hcol;
            const unsigned short* vg = v + rowbase * DD + hcol;
            #pragma unroll
            for (int i = 0; i < 4; i++) {
                const int r0 = wave * 16 + i * 4;
                const int row = r0 + klrow;
                const int gch = klch ^ (row & 7);
                gld16(kg + (size_t)row * DD + gch * 8, &Ks[0][r0 * 128]);
            }
            vr0 = *(const uint4*)(vg + (size_t)(2 * pr) * DD + hc);
            vr1 = *(const uint4*)(vg + (size_t)(2 * pr) * DD + hc + 8);
            vr2 = *(const uint4*)(vg + (size_t)(2 * pr + 1) * DD + hc);
            vr3 = *(const uint4*)(vg + (size_t)(2 * pr + 1) * DD + hc + 8);
        }

        for (int kt = 0; kt < nkt; kt++) {
            const int cur = kt & 1;
            __syncthreads();   // barrier A: drains K/V prefetch; prior tile reads done
            if (kt + 1 < nkt) {
                const unsigned short* kg = k + (rowbase + (kt + 1) * 64) * DD + hcol;
                #pragma unroll
                for (int i = 0; i < 4; i++) {
                    const int r0 = wave * 16 + i * 4;
                    const int row = r0 + klrow;
                    const int gch = klch ^ (row & 7);
                    gld16(kg + (size_t)row * DD + gch * 8, &Ks[cur ^ 1][r0 * 128]);
                }
            }
            {
                const unsigned short* s0 = (const unsigned short*)&vr0;
                const unsigned short* s1 = (const unsigned short*)&vr1;
                const unsigned short* s2 = (const unsigned short*)&vr2;
                const unsigned short* s3 = (const unsigned short*)&vr3;
                #pragma unroll
                for (int jj = 0; jj < 8; jj++) {
                    *(uint32_t*)(&Vts[(hc + jj) * 64 + vsw0]) =
                        (uint32_t)s0[jj] | ((uint32_t)s2[jj] << 16);
                    *(uint32_t*)(&Vts[(hc + 8 + jj) * 64 + vsw1]) =
                        (uint32_t)s1[jj] | ((uint32_t)s3[jj] << 16);
                }
            }
            if (kt + 1 < nkt) {
                const unsigned short* vg = v + (rowbase + (kt + 1) * 64) * DD + hcol;
                vr0 = *(const uint4*)(vg + (size_t)(2 * pr) * DD + hc);
                vr1 = *(const uint4*)(vg + (size_t)(2 * pr) * DD + hc + 8);
                vr2 = *(const uint4*)(vg + (size_t)(2 * pr + 1) * DD + hc);
                vr3 = *(const uint4*)(vg + (size_t)(2 * pr + 1) * DD + hc + 8);
            }
            const unsigned short* ksc = &Ks[cur][0];
            f32x4 accs[4];
            #pragma unroll
            for (int j = 0; j < 4; j++) accs[j] = zf;
            __builtin_amdgcn_s_setprio(1);
            #pragma unroll
            for (int j = 0; j < 4; j++)
                #pragma unroll
                for (int kk = 0; kk < 4; kk++) {
                    bf16x8 bk = *(const bf16x8*)(&ksc[(j * 16 + l15) * 128 +
                                                      (((kk * 4 + lq) ^ (l15 & 7)) * 8)]);
                    accs[j] = MF(aq[kk], bk, accs[j]);
                }
            __builtin_amdgcn_s_setprio(0);
            const int kbase = kt * 64;
            float rowmax[4] = {-1e30f, -1e30f, -1e30f, -1e30f};
            #pragma unroll
            for (int j = 0; j < 4; j++) {
                const int kp = kbase + j * 16 + l15;
                #pragma unroll
                for (int r = 0; r < 4; r++) {
                    float s = accs[j][r] * scale;
                    s = (kp > qp0 + r) ? -1e30f : s;
                    accs[j][r] = s;
                    rowmax[r] = fmaxf(rowmax[r], s);
                }
            }
            #pragma unroll
            for (int r = 0; r < 4; r++) {
                float mx = rowmax[r];
                mx = fmaxf(mx, __shfl_xor(mx, 1, 64));
                mx = fmaxf(mx, __shfl_xor(mx, 2, 64));
                mx = fmaxf(mx, __shfl_xor(mx, 4, 64));
                mx = fmaxf(mx, __shfl_xor(mx, 8, 64));
                float m_new = fmaxf(m_i[r], mx);
                float al = __expf(m_i[r] - m_new);
                m_i[r] = m_new;
                l_i[r] *= al;
                #pragma unroll
                for (int jh = 0; jh < 8; jh++) acc_o[jh][r] *= al;
            }
            float rowsum[4] = {0.f, 0.f, 0.f, 0.f};
            #pragma unroll
            for (int j = 0; j < 4; j++)
                #pragma unroll
                for (int r = 0; r < 4; r++) {
                    float p = __expf(accs[j][r] - m_i[r]);
                    rowsum[r] += p;
                    Pw[(lq * 4 + r) * LPP + j * 16 + l15] = f2bf(p);
                }
            #pragma unroll
            for (int r = 0; r < 4; r++) {
                float s = rowsum[r];
                s += __shfl_xor(s, 1, 64);
                s += __shfl_xor(s, 2, 64);
                s += __shfl_xor(s, 4, 64);
                s += __shfl_xor(s, 8, 64);
                l_i[r] += s;
            }
            __syncthreads();   // barrier B: V(kt) scatter + P visible
            bf16x8 ap[2];
            #pragma unroll
            for (int kk = 0; kk < 2; kk++)
                ap[kk] = *(const bf16x8*)(&Pw[l15 * LPP + kk * 32 + lq * 8]);
            __builtin_amdgcn_s_setprio(1);
            #pragma unroll
            for (int jh = 0; jh < 8; jh++) {
                const int hd = jh * 16 + l15;
                const int vswz = ((hd >> 3) & 7) << 3;
                #pragma unroll
                for (int kk = 0; kk < 2; kk++) {
                    bf16x8 bv = *(const bf16x8*)(&Vts[hd * 64 + ((kk * 32 + lq * 8) ^ vswz)]);
                    acc_o[jh] = MF(ap[kk], bv, acc_o[jh]);
                }
            }
            __builtin_amdgcn_s_setprio(0);
        }
        #pragma unroll
        for (int jh = 0; jh < 8; jh++) {
            const int col = hcol + jh * 16 + l15;
            #pragma unroll
            for (int r = 0; r < 4; r++)
                o[(rowbase + qp0 + r) * DD + col] = f2bf(acc_o[jh][r] * (1.0f / l_i[r]));
        }
    }
}

extern "C" void kernel_launch(void* const* d_in, const int* in_sizes, int n_in,
                              void* d_out, int out_size, void* d_ws, size_t ws_size,
                              hipStream_t stream) {
    const float* x      = (const float*)d_in[0];
    // d_in[1] = attn_mask: deterministic causal tril -> handled analytically
    const float* w_norm = (const float*)d_in[2];
    const float* wq     = (const float*)d_in[3];
    const float* wk     = (const float*)d_in[4];
    const float* wv     = (const float*)d_in[5];
    const float* wo     = (const float*)d_in[6];

    unsigned short* wbf = (unsigned short*)d_ws;                 // [4][D*D]
    unsigned short* xn  = wbf + (size_t)4 * DD * DD;             // [BT][D]
    unsigned short* qb  = xn + (size_t)BTT * DD;
    unsigned short* kb  = qb + (size_t)BTT * DD;
    unsigned short* vb  = kb + (size_t)BTT * DD;
    unsigned short* ab  = vb + (size_t)BTT * DD;

    convert_w<<<8192, 256, 0, stream>>>(wq, wk, wv, wo, wbf);
    rmsnorm_k<<<BTT, 256, 0, stream>>>(x, w_norm, xn);
    dim3 gqkv(32, 24);
    gemm_qkv<<<gqkv, 512, 0, stream>>>(xn, wbf, qb);
    dim3 gattn(16, NHH, 2);
    attn_fused<<<gattn, 256, 0, stream>>>(qb, kb, vb, ab);
    dim3 gout(32, 8);
    gemm_out<<<gout, 512, 0, stream>>>(ab, wbf + (size_t)3 * DD * DD, (float*)d_out);
}

// Round 10
// 444.433 us; speedup vs baseline: 1.0784x; 1.0257x over previous
//
#include <hip/hip_runtime.h>
#include <stdint.h>

#define TT 2048
#define DD 2048
#define NHH 16
#define HDD 128
#define BTT 4096   // B*T

typedef __attribute__((ext_vector_type(8))) short bf16x8;
typedef __attribute__((ext_vector_type(4))) float f32x4;

#define MF(a, b, c) __builtin_amdgcn_mfma_f32_16x16x32_bf16(a, b, c, 0, 0, 0)

__device__ __forceinline__ unsigned short f2bf(float f) {
    union { float f; uint32_t u; } v; v.f = f;
    uint32_t u = v.u;
    u += 0x7fffu + ((u >> 16) & 1u);   // RNE
    return (unsigned short)(u >> 16);
}

// async global->LDS, 16B per lane. LDS dest = wave-uniform base + lane*16B.
__device__ __forceinline__ void gld16(const unsigned short* g, unsigned short* l) {
    __builtin_amdgcn_global_load_lds(
        (const __attribute__((address_space(1))) unsigned int*)g,
        (__attribute__((address_space(3))) unsigned int*)l, 16, 0, 0);
}

// ---------------- weight fp32 -> bf16 cast ----------------
__global__ __launch_bounds__(256) void convert_w(const float* __restrict__ wq,
                                                 const float* __restrict__ wk,
                                                 const float* __restrict__ wv,
                                                 const float* __restrict__ wo,
                                                 unsigned short* __restrict__ out) {
    size_t gid = (size_t)blockIdx.x * 256 + threadIdx.x;
    size_t base = gid * 8;
    int which = (int)(base >> 22);
    const float* src = which == 0 ? wq : which == 1 ? wk : which == 2 ? wv : wo;
    size_t off = base & 4194303u;
    float4 a = ((const float4*)(src + off))[0];
    float4 b = ((const float4*)(src + off))[1];
    union { unsigned short us[8]; uint4 v; } pk;
    pk.us[0] = f2bf(a.x); pk.us[1] = f2bf(a.y); pk.us[2] = f2bf(a.z); pk.us[3] = f2bf(a.w);
    pk.us[4] = f2bf(b.x); pk.us[5] = f2bf(b.y); pk.us[6] = f2bf(b.z); pk.us[7] = f2bf(b.w);
    *(uint4*)(out + base) = pk.v;
}

// ---------------- RMSNorm fp32 -> bf16 ----------------
__global__ __launch_bounds__(256) void rmsnorm_k(const float* __restrict__ x,
                                                 const float* __restrict__ w,
                                                 unsigned short* __restrict__ xn) {
    const int row = blockIdx.x;
    const int tid = threadIdx.x;
    const float* xr = x + (size_t)row * DD;
    float4 a = ((const float4*)xr)[tid * 2];
    float4 b = ((const float4*)xr)[tid * 2 + 1];
    float ss = a.x*a.x + a.y*a.y + a.z*a.z + a.w*a.w
             + b.x*b.x + b.y*b.y + b.z*b.z + b.w*b.w;
    #pragma unroll
    for (int m = 1; m < 64; m <<= 1) ss += __shfl_xor(ss, m, 64);
    __shared__ float wss[4];
    if ((tid & 63) == 0) wss[tid >> 6] = ss;
    __syncthreads();
    float total = wss[0] + wss[1] + wss[2] + wss[3];
    float norm = sqrtf(total) * 0.022097086912079612f;
    float inv = 1.0f / (norm + 1e-8f);
    float4 wa = ((const float4*)w)[tid * 2];
    float4 wb = ((const float4*)w)[tid * 2 + 1];
    union { unsigned short us[8]; uint4 v; } pk;
    pk.us[0] = f2bf(wa.x * a.x * inv); pk.us[1] = f2bf(wa.y * a.y * inv);
    pk.us[2] = f2bf(wa.z * a.z * inv); pk.us[3] = f2bf(wa.w * a.w * inv);
    pk.us[4] = f2bf(wb.x * b.x * inv); pk.us[5] = f2bf(wb.y * b.y * inv);
    pk.us[6] = f2bf(wb.z * b.z * inv); pk.us[7] = f2bf(wb.w * b.w * inv);
    ((uint4*)(xn + (size_t)row * DD))[tid] = pk.v;
}

// ---------------- qkv core: 128x256 reg-staged depth-2 counted-vmcnt (R9, measured 165us) ----------------
// Normal loads engage cross-block L2 sharing (R8: FETCH 1.15GB->144MB, conflicts=0).
// 768 blocks @48KB LDS -> 3 blocks/CU, 24 waves/CU: cross-block TLP hides the chain.
__device__ __forceinline__ void gemm_rs_core(const unsigned short* __restrict__ Ag,
                                             const unsigned short* __restrict__ Bg,
                                             unsigned short* lds, f32x4 acc[4][4]) {
    const int tid = threadIdx.x;
    const int wave = tid >> 6, lane = tid & 63;
    const int wm = wave >> 2, wn = wave & 3;
    const int l15 = lane & 15, lq = lane >> 4;
    const unsigned short* ga  = Ag + (size_t)(wave * 16 + l15) * DD + lq * 8;
    const unsigned short* gb0 = Bg + (size_t)(wave * 32 + l15) * DD + lq * 8;
    const unsigned short* gb1 = Bg + (size_t)(wave * 32 + 16 + l15) * DD + lq * 8;
    const int da  = wave * 512 + lane * 8;
    const int db0 = 4096 + wave * 1024 + lane * 8;
    const int db1 = 4096 + wave * 1024 + 512 + lane * 8;
    const int ra = (wm * 4) * 512 + lq * 128 + l15 * 8;
    const int rb = 4096 + (wn * 4) * 512 + lq * 128 + l15 * 8;

    uint4 pA, pB0, pB1, qA, qB0, qB1;

    pA  = *(const uint4*)(ga);
    pB0 = *(const uint4*)(gb0);
    pB1 = *(const uint4*)(gb1);
    asm volatile("s_waitcnt vmcnt(0)" ::: "memory");
    *(uint4*)(lds + da)  = pA;
    *(uint4*)(lds + db0) = pB0;
    *(uint4*)(lds + db1) = pB1;
    pA  = *(const uint4*)(ga + 32);
    pB0 = *(const uint4*)(gb0 + 32);
    pB1 = *(const uint4*)(gb1 + 32);
    asm volatile("s_waitcnt lgkmcnt(0)" ::: "memory");
    __builtin_amdgcn_s_barrier();

    auto body = [&](int kt, int cur, int nxt,
                    uint4& cpA, uint4& cpB0, uint4& cpB1,
                    uint4& cqA, uint4& cqB0, uint4& cqB1) {
        const bool h2 = (kt + 2 < 64);
        if (h2) {
            const int ko = (kt + 2) * 32;
            cqA  = *(const uint4*)(ga + ko);
            cqB0 = *(const uint4*)(gb0 + ko);
            cqB1 = *(const uint4*)(gb1 + ko);
        }
        const unsigned short* ac = lds + cur + ra;
        const unsigned short* bc = lds + cur + rb;
        bf16x8 a[4], b[4];
        #pragma unroll
        for (int i = 0; i < 4; i++) a[i] = *(const bf16x8*)(ac + i * 512);
        #pragma unroll
        for (int n = 0; n < 4; n++) b[n] = *(const bf16x8*)(bc + n * 512);
        asm volatile("s_waitcnt lgkmcnt(0)" ::: "memory");
        __builtin_amdgcn_sched_barrier(0);
        __builtin_amdgcn_s_setprio(1);
        #pragma unroll
        for (int i = 0; i < 4; i++)
            #pragma unroll
            for (int n = 0; n < 4; n++)
                acc[i][n] = MF(a[i], b[n], acc[i][n]);
        __builtin_amdgcn_s_setprio(0);
        if (kt + 1 < 64) {
            if (h2) { asm volatile("s_waitcnt vmcnt(3)" ::: "memory"); }
            else    { asm volatile("s_waitcnt vmcnt(0)" ::: "memory"); }
            __builtin_amdgcn_sched_barrier(0);
            *(uint4*)(lds + nxt + da)  = cpA;
            *(uint4*)(lds + nxt + db0) = cpB0;
            *(uint4*)(lds + nxt + db1) = cpB1;
            asm volatile("s_waitcnt lgkmcnt(0)" ::: "memory");
            __builtin_amdgcn_sched_barrier(0);
        }
        __builtin_amdgcn_s_barrier();
    };

    for (int k2 = 0; k2 < 32; k2++) {
        body(2 * k2,     0,     12288, pA, pB0, pB1, qA, qB0, qB1);
        body(2 * k2 + 1, 12288, 0,     qA, qB0, qB1, pA, pB0, pB1);
    }
}

// ---------------- out core: 128x256 gld16 triple-buffer counted-vmcnt (R7, measured ~64us) ----------------
// gemm_out has only 256 blocks -> 1 block/CU: reg-staged chain has no TLP cover there.
// gld16 async DMA progresses without wave TLP; fetch-bound at 384MB/6.1TB/s ~= 63us.
__device__ __forceinline__ void stage_tile(const unsigned short* __restrict__ Ag,
                                           const unsigned short* __restrict__ Bg,
                                           int k0, unsigned short* buf,
                                           int swA, int swB, size_t goff) {
    #pragma unroll
    for (int c = 0; c < 2; c++)
        gld16(Ag + (size_t)(swA + c * 8) * DD + k0 + goff, buf + (swA + c * 8) * 64);
    #pragma unroll
    for (int c = 0; c < 4; c++)
        gld16(Bg + (size_t)(swB + c * 8) * DD + k0 + goff, buf + 8192 + (swB + c * 8) * 64);
}

__device__ __forceinline__ void gemm_tb_core(const unsigned short* __restrict__ Ag,
                                             const unsigned short* __restrict__ Bg,
                                             unsigned short* lds, f32x4 acc[4][4]) {
    const int tid = threadIdx.x;
    const int wave = tid >> 6, lane = tid & 63;
    const int wm = wave >> 2, wn = wave & 3;
    const int l15 = lane & 15, lq = lane >> 4, r7 = l15 & 7;
    const int gr = lane >> 3;
    const size_t goff = (size_t)gr * DD + (size_t)(((lane & 7) ^ gr) * 8);
    const int xk0 = (lq ^ r7) * 8;         // k-half 0 chunk (de-swizzled)
    const int xk1 = ((4 + lq) ^ r7) * 8;   // k-half 1 chunk
    const int aro = (wm * 64 + l15) * 64;
    const int bro = 8192 + (wn * 64 + l15) * 64;
    const int swA = wave * 16;
    const int swB = wave * 32;
    unsigned short* p0 = lds;            // compute buffer (tile kt)
    unsigned short* p1 = lds + 24576;    // tile kt+1
    unsigned short* p2 = lds + 49152;    // tile kt+2 (stage target)

    stage_tile(Ag, Bg, 0, p0, swA, swB, goff);
    stage_tile(Ag, Bg, 64, p1, swA, swB, goff);
    asm volatile("s_waitcnt vmcnt(6)" ::: "memory");
    __builtin_amdgcn_sched_barrier(0);
    __builtin_amdgcn_s_barrier();

    for (int kt = 0; kt < 32; kt++) {
        if (kt + 2 < 32)
            stage_tile(Ag, Bg, (kt + 2) * 64, p2, swA, swB, goff);
        const unsigned short* ac = p0 + aro;
        const unsigned short* bc = p0 + bro;
        bf16x8 a[4][2], b[4][2];
        #pragma unroll
        for (int m = 0; m < 4; m++) {
            a[m][0] = *(const bf16x8*)(ac + m * 1024 + xk0);
            a[m][1] = *(const bf16x8*)(ac + m * 1024 + xk1);
        }
        #pragma unroll
        for (int n = 0; n < 4; n++) {
            b[n][0] = *(const bf16x8*)(bc + n * 1024 + xk0);
            b[n][1] = *(const bf16x8*)(bc + n * 1024 + xk1);
        }
        asm volatile("s_waitcnt lgkmcnt(0)" ::: "memory");
        __builtin_amdgcn_sched_barrier(0);
        __builtin_amdgcn_s_setprio(1);
        #pragma unroll
        for (int m = 0; m < 4; m++)
            #pragma unroll
            for (int n = 0; n < 4; n++) {
                acc[m][n] = MF(a[m][0], b[n][0], acc[m][n]);
                acc[m][n] = MF(a[m][1], b[n][1], acc[m][n]);
            }
        __builtin_amdgcn_s_setprio(0);
        if (kt + 1 < 32) {
            if (kt + 2 < 32) { asm volatile("s_waitcnt vmcnt(6)" ::: "memory"); }
            else             { asm volatile("s_waitcnt vmcnt(0)" ::: "memory"); }
            __builtin_amdgcn_sched_barrier(0);
        }
        __builtin_amdgcn_s_barrier();
        unsigned short* t = p0; p0 = p1; p1 = p2; p2 = t;
    }
}

// fused QKV: 768 blocks (32x8x3) x 512 thr; XCD swizzle -> same-B-panel blocks per XCD
__global__ __launch_bounds__(512) void gemm_qkv(const unsigned short* __restrict__ A,
                                                const unsigned short* __restrict__ W3,
                                                unsigned short* __restrict__ O3) {
    __shared__ __align__(16) unsigned short lds[24576];   // 48 KiB, 2 bufs
    const int orig = blockIdx.y * 32 + blockIdx.x;        // grid (32, 24)
    const int id = (orig & 7) * 96 + (orig >> 3);         // bijective XCD swizzle (768%8==0)
    const int which = id >> 8;
    const int rem = id & 255;
    const int bn = rem >> 5, bm = rem & 31;               // consecutive ids share B panel
    const unsigned short* Bw = W3 + (size_t)which * DD * DD;
    unsigned short* C = O3 + (size_t)which * BTT * DD;
    const int m0 = bm * 128, n0 = bn * 256;
    const f32x4 zf = {0.f, 0.f, 0.f, 0.f};
    f32x4 acc[4][4];
    #pragma unroll
    for (int m = 0; m < 4; m++)
        #pragma unroll
        for (int n = 0; n < 4; n++) acc[m][n] = zf;
    gemm_rs_core(A + (size_t)m0 * DD, Bw + (size_t)n0 * DD, lds, acc);
    const int wave = threadIdx.x >> 6, lane = threadIdx.x & 63;
    const int wm = wave >> 2, wn = wave & 3;
    const int l15 = lane & 15, lq = lane >> 4;
    #pragma unroll
    for (int m = 0; m < 4; m++) {
        const int row = m0 + wm * 64 + m * 16 + lq * 4;
        #pragma unroll
        for (int n = 0; n < 4; n++) {
            const int col = n0 + wn * 64 + n * 16 + l15;
            #pragma unroll
            for (int r = 0; r < 4; r++)
                C[(size_t)(row + r) * DD + col] = f2bf(acc[m][n][r]);
        }
    }
}

// final proj, fp32 out: 256 blocks (32x8) x 512 thr, gld16 triple-buffer core
__global__ __launch_bounds__(512, 2) void gemm_out(const unsigned short* __restrict__ A,
                                                   const unsigned short* __restrict__ Bw,
                                                   float* __restrict__ C) {
    __shared__ __align__(16) unsigned short lds[73728];   // 144 KiB, 3 bufs
    const int orig = blockIdx.y * 32 + blockIdx.x;        // grid (32, 8)
    const int id = (orig & 7) * 32 + (orig >> 3);         // bijective XCD swizzle (256%8==0)
    const int bn = id >> 5, bm = id & 31;
    const int m0 = bm * 128, n0 = bn * 256;
    const f32x4 zf = {0.f, 0.f, 0.f, 0.f};
    f32x4 acc[4][4];
    #pragma unroll
    for (int m = 0; m < 4; m++)
        #pragma unroll
        for (int n = 0; n < 4; n++) acc[m][n] = zf;
    gemm_tb_core(A + (size_t)m0 * DD, Bw + (size_t)n0 * DD, lds, acc);
    const int wave = threadIdx.x >> 6, lane = threadIdx.x & 63;
    const int wm = wave >> 2, wn = wave & 3;
    const int l15 = lane & 15, lq = lane >> 4;
    #pragma unroll
    for (int m = 0; m < 4; m++) {
        const int row = m0 + wm * 64 + m * 16 + lq * 4;
        #pragma unroll
        for (int n = 0; n < 4; n++) {
            const int col = n0 + wn * 64 + n * 16 + l15;
            #pragma unroll
            for (int r = 0; r < 4; r++)
                C[(size_t)(row + r) * DD + col] = acc[m][n][r];
        }
    }
}

// ---------------- fused causal flash attention, paired q-tiles (measured 128us) ----------------
__global__ __launch_bounds__(256) void attn_fused(const unsigned short* __restrict__ q,
                                                  const unsigned short* __restrict__ k,
                                                  const unsigned short* __restrict__ v,
                                                  unsigned short* __restrict__ o) {
    constexpr int LPP = 72;   // 64 + 8 pad
    __shared__ __align__(16) unsigned short Ks[2][64 * 128];
    __shared__ __align__(16) unsigned short Vts[128 * 64];
    __shared__ __align__(16) unsigned short Ps[4 * 16 * LPP];
    const int h = blockIdx.y, b = blockIdx.z;
    const int tid = threadIdx.x, wave = tid >> 6, lane = tid & 63;
    const int l15 = lane & 15, lq = lane >> 4;
    const size_t rowbase = (size_t)b * TT;
    const int hcol = h * HDD;
    const float scale = 0.08838834764831845f;  // HD^-0.5
    unsigned short* Pw = Ps + wave * 16 * LPP;
    const f32x4 zf = {0.f, 0.f, 0.f, 0.f};

    uint4 vr0, vr1, vr2, vr3;
    const int pr = tid >> 3;            // 0..31
    const int hc = (tid & 7) * 16;      // 0,16,...,112
    const int vsw0 = (2 * pr) ^ (((hc >> 3) & 7) << 3);
    const int vsw1 = (2 * pr) ^ ((((hc + 8) >> 3) & 7) << 3);

    const int klrow = lane >> 4;        // 0..3
    const int klch  = lane & 15;

    for (int half = 0; half < 2; half++) {
        const int qj = (half == 0) ? blockIdx.x : 31 - blockIdx.x;
        const int qt0 = qj * 64;
        bf16x8 aq[4];
        {
            const unsigned short* qrp = q + (rowbase + qt0 + wave * 16 + l15) * DD + hcol;
            #pragma unroll
            for (int kk = 0; kk < 4; kk++)
                aq[kk] = *(const bf16x8*)(qrp + kk * 32 + lq * 8);
        }
        f32x4 acc_o[8];
        #pragma unroll
        for (int jh = 0; jh < 8; jh++) acc_o[jh] = zf;
        float m_i[4], l_i[4];
        #pragma unroll
        for (int r = 0; r < 4; r++) { m_i[r] = -1e30f; l_i[r] = 0.f; }
        const int qp0 = qt0 + wave * 16 + lq * 4;
        const int nkt = qj + 1;

        __syncthreads();
        {
            const unsigned short* kg = k + rowbase * DD + hcol;
            const unsigned short* vg = v + rowbase * DD + hcol;
            #pragma unroll
            for (int i = 0; i < 4; i++) {
                const int r0 = wave * 16 + i * 4;
                const int row = r0 + klrow;
                const int gch = klch ^ (row & 7);
                gld16(kg + (size_t)row * DD + gch * 8, &Ks[0][r0 * 128]);
            }
            vr0 = *(const uint4*)(vg + (size_t)(2 * pr) * DD + hc);
            vr1 = *(const uint4*)(vg + (size_t)(2 * pr) * DD + hc + 8);
            vr2 = *(const uint4*)(vg + (size_t)(2 * pr + 1) * DD + hc);
            vr3 = *(const uint4*)(vg + (size_t)(2 * pr + 1) * DD + hc + 8);
        }

        for (int kt = 0; kt < nkt; kt++) {
            const int cur = kt & 1;
            __syncthreads();   // barrier A: drains K/V prefetch; prior tile reads done
            if (kt + 1 < nkt) {
                const unsigned short* kg = k + (rowbase + (kt + 1) * 64) * DD + hcol;
                #pragma unroll
                for (int i = 0; i < 4; i++) {
                    const int r0 = wave * 16 + i * 4;
                    const int row = r0 + klrow;
                    const int gch = klch ^ (row & 7);
                    gld16(kg + (size_t)row * DD + gch * 8, &Ks[cur ^ 1][r0 * 128]);
                }
            }
            {
                const unsigned short* s0 = (const unsigned short*)&vr0;
                const unsigned short* s1 = (const unsigned short*)&vr1;
                const unsigned short* s2 = (const unsigned short*)&vr2;
                const unsigned short* s3 = (const unsigned short*)&vr3;
                #pragma unroll
                for (int jj = 0; jj < 8; jj++) {
                    *(uint32_t*)(&Vts[(hc + jj) * 64 + vsw0]) =
                        (uint32_t)s0[jj] | ((uint32_t)s2[jj] << 16);
                    *(uint32_t*)(&Vts[(hc + 8 + jj) * 64 + vsw1]) =
                        (uint32_t)s1[jj] | ((uint32_t)s3[jj] << 16);
                }
            }
            if (kt + 1 < nkt) {
                const unsigned short* vg = v + (rowbase + (kt + 1) * 64) * DD + hcol;
                vr0 = *(const uint4*)(vg + (size_t)(2 * pr) * DD + hc);
                vr1 = *(const uint4*)(vg + (size_t)(2 * pr) * DD + hc + 8);
                vr2 = *(const uint4*)(vg + (size_t)(2 * pr + 1) * DD + hc);
                vr3 = *(const uint4*)(vg + (size_t)(2 * pr + 1) * DD + hc + 8);
            }
            const unsigned short* ksc = &Ks[cur][0];
            f32x4 accs[4];
            #pragma unroll
            for (int j = 0; j < 4; j++) accs[j] = zf;
            __builtin_amdgcn_s_setprio(1);
            #pragma unroll
            for (int j = 0; j < 4; j++)
                #pragma unroll
                for (int kk = 0; kk < 4; kk++) {
                    bf16x8 bk = *(const bf16x8*)(&ksc[(j * 16 + l15) * 128 +
                                                      (((kk * 4 + lq) ^ (l15 & 7)) * 8)]);
                    accs[j] = MF(aq[kk], bk, accs[j]);
                }
            __builtin_amdgcn_s_setprio(0);
            const int kbase = kt * 64;
            float rowmax[4] = {-1e30f, -1e30f, -1e30f, -1e30f};
            #pragma unroll
            for (int j = 0; j < 4; j++) {
                const int kp = kbase + j * 16 + l15;
                #pragma unroll
                for (int r = 0; r < 4; r++) {
                    float s = accs[j][r] * scale;
                    s = (kp > qp0 + r) ? -1e30f : s;
                    accs[j][r] = s;
                    rowmax[r] = fmaxf(rowmax[r], s);
                }
            }
            #pragma unroll
            for (int r = 0; r < 4; r++) {
                float mx = rowmax[r];
                mx = fmaxf(mx, __shfl_xor(mx, 1, 64));
                mx = fmaxf(mx, __shfl_xor(mx, 2, 64));
                mx = fmaxf(mx, __shfl_xor(mx, 4, 64));
                mx = fmaxf(mx, __shfl_xor(mx, 8, 64));
                float m_new = fmaxf(m_i[r], mx);
                float al = __expf(m_i[r] - m_new);
                m_i[r] = m_new;
                l_i[r] *= al;
                #pragma unroll
                for (int jh = 0; jh < 8; jh++) acc_o[jh][r] *= al;
            }
            float rowsum[4] = {0.f, 0.f, 0.f, 0.f};
            #pragma unroll
            for (int j = 0; j < 4; j++)
                #pragma unroll
                for (int r = 0; r < 4; r++) {
                    float p = __expf(accs[j][r] - m_i[r]);
                    rowsum[r] += p;
                    Pw[(lq * 4 + r) * LPP + j * 16 + l15] = f2bf(p);
                }
            #pragma unroll
            for (int r = 0; r < 4; r++) {
                float s = rowsum[r];
                s += __shfl_xor(s, 1, 64);
                s += __shfl_xor(s, 2, 64);
                s += __shfl_xor(s, 4, 64);
                s += __shfl_xor(s, 8, 64);
                l_i[r] += s;
            }
            __syncthreads();   // barrier B: V(kt) scatter + P visible
            bf16x8 ap[2];
            #pragma unroll
            for (int kk = 0; kk < 2; kk++)
                ap[kk] = *(const bf16x8*)(&Pw[l15 * LPP + kk * 32 + lq * 8]);
            __builtin_amdgcn_s_setprio(1);
            #pragma unroll
            for (int jh = 0; jh < 8; jh++) {
                const int hd = jh * 16 + l15;
                const int vswz = ((hd >> 3) & 7) << 3;
                #pragma unroll
                for (int kk = 0; kk < 2; kk++) {
                    bf16x8 bv = *(const bf16x8*)(&Vts[hd * 64 + ((kk * 32 + lq * 8) ^ vswz)]);
                    acc_o[jh] = MF(ap[kk], bv, acc_o[jh]);
                }
            }
            __builtin_amdgcn_s_setprio(0);
        }
        #pragma unroll
        for (int jh = 0; jh < 8; jh++) {
            const int col = hcol + jh * 16 + l15;
            #pragma unroll
            for (int r = 0; r < 4; r++)
                o[(rowbase + qp0 + r) * DD + col] = f2bf(acc_o[jh][r] * (1.0f / l_i[r]));
        }
    }
}

extern "C" void kernel_launch(void* const* d_in, const int* in_sizes, int n_in,
                              void* d_out, int out_size, void* d_ws, size_t ws_size,
                              hipStream_t stream) {
    const float* x      = (const float*)d_in[0];
    // d_in[1] = attn_mask: deterministic causal tril -> handled analytically
    const float* w_norm = (const float*)d_in[2];
    const float* wq     = (const float*)d_in[3];
    const float* wk     = (const float*)d_in[4];
    const float* wv     = (const float*)d_in[5];
    const float* wo     = (const float*)d_in[6];

    unsigned short* wbf = (unsigned short*)d_ws;                 // [4][D*D]
    unsigned short* xn  = wbf + (size_t)4 * DD * DD;             // [BT][D]
    unsigned short* qb  = xn + (size_t)BTT * DD;
    unsigned short* kb  = qb + (size_t)BTT * DD;
    unsigned short* vb  = kb + (size_t)BTT * DD;
    unsigned short* ab  = vb + (size_t)BTT * DD;

    convert_w<<<8192, 256, 0, stream>>>(wq, wk, wv, wo, wbf);
    rmsnorm_k<<<BTT, 256, 0, stream>>>(x, w_norm, xn);
    dim3 gqkv(32, 24);
    gemm_qkv<<<gqkv, 512, 0, stream>>>(xn, wbf, qb);
    dim3 gattn(16, NHH, 2);
    attn_fused<<<gattn, 256, 0, stream>>>(qb, kb, vb, ab);
    dim3 gout(32, 8);
    gemm_out<<<gout, 512, 0, stream>>>(ab, wbf + (size_t)3 * DD * DD, (float*)d_out);
}